// Round 4
// baseline (90.831 us; speedup 1.0000x reference)
//
#include <hip/hip_runtime.h>

#define B_TOTAL 8192
#define IN_DIM  64
#define OUT_DIM 64
#define NSPL    8
#define NBRK    20
#define NINT    19

#define BTILE   16   // rows of x per block
#define RPT     4    // rows per thread-group (4 waves * 4 = 16)

// Param table: [IN_DIM][OUT_DIM][8] floats = {k3, b4, k2, c1, c5, c6, c7, c8}
//   k3 = b3*log2(e), k2 = b2*ln2, c1 = b1*G*ln2, c5..c8 = b5..b8*G, G = softplus(raw_gamma)/OUT
__device__ float g_table[IN_DIM * OUT_DIM * 8];

// 64 blocks x 64 threads. breaks (160 f) + coefs (608 f) staged into LDS with
// one coalesced burst (192 float4 across 64 lanes) -> ONE cold-HBM round trip
// instead of serialized dependent misses inside the spline loop.
__global__ __launch_bounds__(64) void precompute_params(
    const float* __restrict__ raw_gamma, const float* __restrict__ w,
    const float* __restrict__ breaks, const float* __restrict__ coefs,
    const float* __restrict__ mu_p, const float* __restrict__ sigma_p)
{
    __shared__ float s_breaks[NSPL * NBRK];       // 160 floats
    __shared__ float s_coefs[NSPL * NINT * 4];    // 608 floats
    const int t = threadIdx.x;

    {
        const float4* bsrc = (const float4*)breaks;
        const float4* csrc = (const float4*)coefs;
        float4* bdst = (float4*)s_breaks;
        float4* cdst = (float4*)s_coefs;
        if (t < 40) bdst[t] = bsrc[t];                       // 160 floats
        #pragma unroll
        for (int k = 0; k < 3; ++k) {                        // 152 float4
            int idx = t + k * 64;
            if (idx < 152) cdst[idx] = csrc[idx];
        }
    }

    int gid = blockIdx.x * 64 + t;   // gid = o*IN_DIM + i (w layout row-major)
    int o = gid >> 6;
    int i = gid & 63;

    float mu = mu_p[0], sigma = sigma_p[0];
    float wc = fminf(fmaxf(w[gid], -5.5f), 37.9f);
    float g  = raw_gamma[gid];
    float wn = (wc - mu) / sigma;

    __syncthreads();

    float bs[NSPL];
    #pragma unroll
    for (int s = 0; s < NSPL; ++s) {
        const float* br = s_breaks + s * NBRK;
        float lo = br[0];
        float hi = br[NBRK - 1] - 1e-6f;
        float wl = fminf(fmaxf(wn, lo), hi);
        // searchsorted(br, wl, 'left') == count of br[k] < wl
        int cnt = 0;
        #pragma unroll
        for (int k = 0; k < NBRK; ++k) cnt += (br[k] < wl) ? 1 : 0;
        int idx = cnt - 1;
        idx = idx < 0 ? 0 : (idx > NINT - 1 ? NINT - 1 : idx);
        const float* a = s_coefs + (s * NINT + idx) * 4;
        float tt = wl - br[idx];
        bs[s] = ((a[0] * tt + a[1]) * tt + a[2]) * tt + a[3];
    }

    float sp = fmaxf(g, 0.0f) + log1pf(expf(-fabsf(g)));   // stable softplus
    float G = sp * (1.0f / (float)OUT_DIM);

    const float LOG2E = 1.4426950408889634f;
    const float LN2   = 0.6931471805599453f;

    float* t8 = g_table + (i * OUT_DIM + o) * 8;
    t8[0] = bs[2] * LOG2E;     // k3
    t8[1] = bs[3];             // b4
    t8[2] = bs[1] * LN2;       // k2
    t8[3] = bs[0] * G * LN2;   // c1
    t8[4] = bs[4] * G;         // c5
    t8[5] = bs[5] * G;         // c6
    t8[6] = bs[6] * G;         // c7
    t8[7] = bs[7] * G;         // c8
}

// One row's contribution. xr is WAVE-UNIFORM (lanes differ only in o).
// relu output is {+0} U (0,inf), so xr>0 <=> float bits (as int) > 0;
// readfirstlane makes the test provably scalar -> s_cmp + s_cbranch_scc,
// no v_cmp / exec-mask save-restore per row. Skipped rows contribute
// exactly 0 (0^b4=0 -> both log1p terms 0, poly(0)=0).
__device__ __forceinline__ void row_contrib(float xr, const float4& p0,
                                            const float4& p1, float& acc)
{
    if (__builtin_amdgcn_readfirstlane(__float_as_int(xr)) > 0) {
        // e = 2^(k3*x) = exp(b3*x)
        float e  = __builtin_amdgcn_exp2f(p0.x * xr);
        // pw = (e-1)^b4 = 2^(b4*log2(e-1))
        float lb = __builtin_amdgcn_logf(e - 1.0f);
        float pw = __builtin_amdgcn_exp2f(p0.y * lb);
        // t1 = log2(1+pw); t2 = log2(1 + k2*t1); contribution c1*t2 (ln2 folded into c1,k2)
        float t1 = __builtin_amdgcn_logf(1.0f + pw);
        float t2 = __builtin_amdgcn_logf(fmaf(p0.z, t1, 1.0f));
        // poly: c5*x + c6*x^2 + c7*x^3 + c8*x^4 (Horner)
        float q = fmaf(p1.w, xr, p1.z);
        q = fmaf(q, xr, p1.y);
        q = fmaf(q, xr, p1.x);
        acc = fmaf(q, xr, acc);
        acc = fmaf(p0.w, t2, acc);
    }
}

__global__ __launch_bounds__(256) void log_act_kernel(
    const float* __restrict__ x, float* __restrict__ out)
{
    // Transposed tile: xs_t[i][row]. Per-i fragment for a thread's 4 rows is
    // 16B contiguous -> ONE broadcast ds_read_b128 (same addr across lanes,
    // conflict-free).
    __shared__ float xs_t[IN_DIM][BTILE];
    const int tid = threadIdx.x;
    const int b0  = blockIdx.x * BTILE;

    // Staging with transpose + ReLU. thread -> (row = tid&15, ig = tid>>4).
    {
        const int row = tid & 15;
        const int ig  = tid >> 4;          // i-group 0..15
        float4 v = *(const float4*)(x + (b0 + row) * IN_DIM + ig * 4);
        xs_t[ig * 4 + 0][row] = fmaxf(v.x, 0.0f);
        xs_t[ig * 4 + 1][row] = fmaxf(v.y, 0.0f);
        xs_t[ig * 4 + 2][row] = fmaxf(v.z, 0.0f);
        xs_t[ig * 4 + 3][row] = fmaxf(v.w, 0.0f);
    }
    __syncthreads();

    const int o  = tid & 63;
    const int bg = tid >> 6;   // 0..3

    float acc[RPT];
    #pragma unroll
    for (int r = 0; r < RPT; ++r) acc[r] = 0.0f;

    const float* tbase = g_table + o * 8;

    for (int i = 0; i < IN_DIM; ++i) {
        const float4* p = (const float4*)(tbase + i * OUT_DIM * 8);
        float4 p0 = p[0];   // k3, b4, k2, c1
        float4 p1 = p[1];   // c5, c6, c7, c8
        float4 xv = *(const float4*)&xs_t[i][bg * RPT];  // broadcast b128

        row_contrib(xv.x, p0, p1, acc[0]);
        row_contrib(xv.y, p0, p1, acc[1]);
        row_contrib(xv.z, p0, p1, acc[2]);
        row_contrib(xv.w, p0, p1, acc[3]);
    }

    #pragma unroll
    for (int r = 0; r < RPT; ++r) {
        int b = b0 + bg * RPT + r;
        out[b * OUT_DIM + o] = acc[r];
    }
}

extern "C" void kernel_launch(void* const* d_in, const int* in_sizes, int n_in,
                              void* d_out, int out_size, void* d_ws, size_t ws_size,
                              hipStream_t stream) {
    const float* x         = (const float*)d_in[0];
    const float* raw_gamma = (const float*)d_in[1];
    const float* w         = (const float*)d_in[2];
    const float* breaks    = (const float*)d_in[3];
    const float* coefs     = (const float*)d_in[4];
    const float* mu_p      = (const float*)d_in[5];
    const float* sigma_p   = (const float*)d_in[6];
    float* out = (float*)d_out;

    precompute_params<<<(OUT_DIM * IN_DIM + 63) / 64, 64, 0, stream>>>(
        raw_gamma, w, breaks, coefs, mu_p, sigma_p);

    log_act_kernel<<<B_TOTAL / BTILE, 256, 0, stream>>>(x, out);
}